// Round 2
// baseline (807.936 us; speedup 1.0000x reference)
//
#include <hip/hip_runtime.h>
#include <hip/hip_bf16.h>

// Problem shapes
#define B_ 256
#define D_ 511
#define H_ 5120

// ---------------- GEMM1: h(bf16) = relu(theta @ w1^T + b1) ----------------
// C[M,N] = A[M,K] * W[N,K]^T  (both K-contiguous, "NT")
#define BM 64
#define BN 64
#define BK 16

__global__ __launch_bounds__(256) void gemm1_relu_kernel(
    const float* __restrict__ A, const float* __restrict__ W,
    const float* __restrict__ bias, __hip_bfloat16* __restrict__ C,
    int M, int N, int K)
{
    __shared__ float As[BK][BM + 1];
    __shared__ float Ws[BK][BN + 1];
    const int t  = threadIdx.x;
    const int tx = t & 15;        // 0..15 -> n
    const int ty = t >> 4;        // 0..15 -> m
    const int m0 = blockIdx.y * BM;
    const int n0 = blockIdx.x * BN;

    float c[4][4] = {};

    for (int k0 = 0; k0 < K; k0 += BK) {
        #pragma unroll
        for (int p = 0; p < 4; ++p) {
            int e   = t + 256 * p;        // 0..1023
            int row = e >> 4;             // 0..63
            int kk  = e & 15;
            int gk  = k0 + kk;
            int gm  = m0 + row;
            int gn  = n0 + row;
            As[kk][row] = (gm < M && gk < K) ? A[(size_t)gm * K + gk] : 0.f;
            Ws[kk][row] = (gn < N && gk < K) ? W[(size_t)gn * K + gk] : 0.f;
        }
        __syncthreads();
        #pragma unroll
        for (int kk = 0; kk < BK; ++kk) {
            float a[4], bv[4];
            #pragma unroll
            for (int i = 0; i < 4; ++i) a[i]  = As[kk][ty * 4 + i];
            #pragma unroll
            for (int j = 0; j < 4; ++j) bv[j] = Ws[kk][tx * 4 + j];
            #pragma unroll
            for (int i = 0; i < 4; ++i)
                #pragma unroll
                for (int j = 0; j < 4; ++j)
                    c[i][j] += a[i] * bv[j];
        }
        __syncthreads();
    }

    #pragma unroll
    for (int i = 0; i < 4; ++i) {
        int gm = m0 + ty * 4 + i;
        if (gm >= M) continue;
        #pragma unroll
        for (int j = 0; j < 4; ++j) {
            int gn = n0 + tx * 4 + j;
            if (gn < N) {
                float v = c[i][j] + bias[gn];
                C[(size_t)gm * N + gn] = __float2bfloat16(v > 0.f ? v : 0.f);
            }
        }
    }
}

// ---------------- GEMM2: phi(fp32, in d_out) = h(bf16) @ w2^T ----------------
// Deterministic, no split-K, no atomics. Grid (16, 8) = 128 blocks.
#define BM2 32
#define BN2 32
#define BK2 32

__global__ __launch_bounds__(256) void gemm2_kernel(
    const __hip_bfloat16* __restrict__ A, const float* __restrict__ W,
    float* __restrict__ C, int M, int N, int K)
{
    __shared__ float As[BK2][BM2 + 2];
    __shared__ float Ws[BK2][BN2 + 2];
    const int t  = threadIdx.x;
    const int tx = t & 15;        // 0..15 -> n pairs
    const int ty = t >> 4;        // 0..15 -> m pairs
    const int m0 = blockIdx.y * BM2;
    const int n0 = blockIdx.x * BN2;

    // loader: each thread loads 4 contiguous k for one row of each tile
    const int lrow = t >> 3;        // 0..31
    const int lk   = (t & 7) * 4;   // 0,4,...,28

    float c[2][2] = {};

    for (int k0 = 0; k0 < K; k0 += BK2) {
        const __hip_bfloat16* Ap = A + (size_t)(m0 + lrow) * K + k0 + lk;
        #pragma unroll
        for (int q = 0; q < 4; ++q)
            As[lk + q][lrow] = __bfloat162float(Ap[q]);
        int gn = n0 + lrow;
        const float* Wp = W + (size_t)gn * K + k0 + lk;
        #pragma unroll
        for (int q = 0; q < 4; ++q)
            Ws[lk + q][lrow] = (gn < N) ? Wp[q] : 0.f;
        __syncthreads();
        #pragma unroll
        for (int kk = 0; kk < BK2; ++kk) {
            float a0 = As[kk][ty * 2 + 0];
            float a1 = As[kk][ty * 2 + 1];
            float b0 = Ws[kk][tx * 2 + 0];
            float b1 = Ws[kk][tx * 2 + 1];
            c[0][0] += a0 * b0; c[0][1] += a0 * b1;
            c[1][0] += a1 * b0; c[1][1] += a1 * b1;
        }
        __syncthreads();
    }

    #pragma unroll
    for (int i = 0; i < 2; ++i) {
        int gm = m0 + ty * 2 + i;
        #pragma unroll
        for (int j = 0; j < 2; ++j) {
            int gn = n0 + tx * 2 + j;
            if (gm < M && gn < N) C[(size_t)gm * N + gn] = c[i][j];
        }
    }
}

// ---------------- quad[b] = (phi_b + b2)^T M_b (phi_b + b2) ----------------
__global__ __launch_bounds__(512) void quad_kernel(
    const float* __restrict__ phi, const float* __restrict__ b2,
    const float* __restrict__ Mmat, float* __restrict__ quad)
{
    __shared__ float phi_s[D_];
    __shared__ float red[8];
    const int b = blockIdx.x;
    const int t = threadIdx.x;

    if (t < D_) phi_s[t] = phi[(size_t)b * D_ + t] + b2[t];
    __syncthreads();

    const int wave = t >> 6;
    const int lane = t & 63;
    const float* Mb = Mmat + (size_t)b * D_ * D_;

    float acc = 0.f;
    for (int i = wave; i < D_; i += 8) {
        const float* row = Mb + (size_t)i * D_;
        float r = 0.f;
        for (int j = lane; j < D_; j += 64) r += row[j] * phi_s[j];
        acc += r * phi_s[i];
    }
    #pragma unroll
    for (int off = 32; off > 0; off >>= 1) acc += __shfl_down(acc, off, 64);
    if (lane == 0) red[wave] = acc;
    __syncthreads();
    if (t == 0) {
        float s = 0.f;
        #pragma unroll
        for (int w = 0; w < 8; ++w) s += red[w];
        quad[b] = s;
    }
}

// -------- final (in-place on d_out): normalize, st-MLP, soft-threshold --------
__global__ __launch_bounds__(256) void final_kernel(
    float* __restrict__ phi_out, const float* __restrict__ b2,
    const float* __restrict__ quad,
    const float* __restrict__ stw1, const float* __restrict__ stb1,
    const float* __restrict__ stw2, const float* __restrict__ stb2)
{
    int idx = blockIdx.x * blockDim.x + threadIdx.x;
    if (idx >= B_ * D_) return;
    int b = idx / D_;
    int d = idx - b * D_;
    float q = quad[b];
    float x = (phi_out[idx] + b2[d]) / sqrtf(q);   // zeta = 1

    float lam = stb2[0];
    #pragma unroll
    for (int k = 0; k < 5; ++k) {
        float g = x * stw1[k] + stb1[k];
        g = g > 0.f ? g : 0.f;
        lam += g * stw2[k];
    }
    lam = fabsf(lam) * 0.1f;

    float ax = fabsf(x) - lam;
    ax = ax > 0.f ? ax : 0.f;
    float s = (x > 0.f) ? 1.f : ((x < 0.f) ? -1.f : 0.f);
    phi_out[idx] = s * ax;
}

extern "C" void kernel_launch(void* const* d_in, const int* in_sizes, int n_in,
                              void* d_out, int out_size, void* d_ws, size_t ws_size,
                              hipStream_t stream)
{
    const float* theta = (const float*)d_in[0];   // [B, D]
    // d_in[1] s_12, d_in[2] w_12 unused
    const float* invT  = (const float*)d_in[3];   // [B, D, D]
    // d_in[4] Theta, d_in[5] col unused
    const float* w1    = (const float*)d_in[6];   // [H, D]
    const float* b1    = (const float*)d_in[7];   // [H]
    const float* w2    = (const float*)d_in[8];   // [D, H]
    const float* b2    = (const float*)d_in[9];   // [D]
    const float* stw1  = (const float*)d_in[10];  // [5]
    const float* stb1  = (const float*)d_in[11];  // [5]
    const float* stw2  = (const float*)d_in[12];  // [5]
    const float* stb2  = (const float*)d_in[13];  // [1]
    float* out = (float*)d_out;                   // phi lives here, rewritten in place

    // Workspace layout (total 2,622,464 bytes — keep footprint minimal):
    __hip_bfloat16* h = (__hip_bfloat16*)d_ws;                 // B*H bf16
    float* quad = (float*)((char*)d_ws + (size_t)B_ * H_ * 2); // B fp32

    // h = relu(theta @ w1^T + b1):  M=256, N=5120, K=511
    gemm1_relu_kernel<<<dim3(H_ / BN, B_ / BM), 256, 0, stream>>>(
        theta, w1, b1, h, B_, H_, D_);

    // phi = h @ w2^T -> d_out: M=256, N=511, K=5120
    gemm2_kernel<<<dim3((D_ + BN2 - 1) / BN2, B_ / BM2), 256, 0, stream>>>(
        h, w2, out, B_, D_, H_);

    // quad[b] = (phi_b + b2)^T invT_b (phi_b + b2)
    quad_kernel<<<B_, 512, 0, stream>>>(out, b2, invT, quad);

    // normalize + st-MLP + soft-threshold, in place on d_out
    final_kernel<<<(B_ * D_ + 255) / 256, 256, 0, stream>>>(
        out, b2, quad, stw1, stb1, stw2, stb2);
}

// Round 3
// 554.751 us; speedup vs baseline: 1.4564x; 1.4564x over previous
//
#include <hip/hip_runtime.h>
#include <hip/hip_bf16.h>

#define B_ 256
#define D_ 511
#define H_ 5120
#define NTOT (D_ * D_)   // 261121

typedef __attribute__((ext_vector_type(4))) float floatx4;
typedef __attribute__((ext_vector_type(8))) short short8;

union I4S8 { int4 i4; short8 s8; };

__device__ __forceinline__ unsigned short f2bf(float v) {
    __hip_bfloat16 h = __float2bfloat16(v);
    return __builtin_bit_cast(unsigned short, h);
}

// byte offset of a 16B chunk in a swizzled 64x64-bf16 LDS tile (row stride 128B)
__device__ __forceinline__ int sw_off(int row, int chunk) {
    return row * 128 + ((chunk ^ (row & 7)) * 16);
}

// ============ GEMM1 (MFMA): h[256][5120] = relu(theta @ w1^T + b1) ============
// theta [256][511] fp32, w1 [5120][511] fp32 (both K-contiguous). K padded to 512.
__global__ __launch_bounds__(256) void gemm1_mfma(
    const float* __restrict__ A, const float* __restrict__ W,
    const float* __restrict__ bias, __hip_bfloat16* __restrict__ Hout)
{
    __shared__ char lds[16384];
    char* Ab = lds;
    char* Bb = lds + 8192;
    const int t = threadIdx.x;
    const int m0 = blockIdx.y * 64;
    const int n0 = blockIdx.x * 64;
    const int lane = t & 63, wave = t >> 6;
    const int wm = (wave & 1) * 32, wn = (wave >> 1) * 32;
    const int lrow = lane & 15, lq = lane >> 4;

    floatx4 acc[2][2] = {};

    const int srow = t >> 6;   // 0..3
    const int sk   = t & 63;   // k within tile (lane-contiguous -> coalesced)

    for (int k0 = 0; k0 < 512; k0 += 64) {
        __syncthreads();
        const bool kv = (k0 + sk) < D_;
        const int wroff = (((sk >> 3) ^ 0) * 0); (void)wroff;
        #pragma unroll
        for (int r = 0; r < 64; r += 4) {
            int row = r + srow;
            float av = kv ? A[(size_t)(m0 + row) * D_ + k0 + sk] : 0.f;
            float bv = kv ? W[(size_t)(n0 + row) * D_ + k0 + sk] : 0.f;
            int off = row * 128 + (((sk >> 3) ^ (row & 7)) * 16) + (sk & 7) * 2;
            *(unsigned short*)(Ab + off) = f2bf(av);
            *(unsigned short*)(Bb + off) = f2bf(bv);
        }
        __syncthreads();
        #pragma unroll
        for (int ks = 0; ks < 2; ++ks) {
            int kc = ks * 4 + lq;
            I4S8 af[2], bf[2];
            #pragma unroll
            for (int i = 0; i < 2; ++i) {
                af[i].i4 = *(const int4*)(Ab + sw_off(wm + i * 16 + lrow, kc));
                bf[i].i4 = *(const int4*)(Bb + sw_off(wn + i * 16 + lrow, kc));
            }
            #pragma unroll
            for (int i = 0; i < 2; ++i)
                #pragma unroll
                for (int j = 0; j < 2; ++j)
                    acc[i][j] = __builtin_amdgcn_mfma_f32_16x16x32_bf16(
                        af[i].s8, bf[j].s8, acc[i][j], 0, 0, 0);
        }
    }

    #pragma unroll
    for (int i = 0; i < 2; ++i) {
        #pragma unroll
        for (int j = 0; j < 2; ++j) {
            int n = n0 + wn + j * 16 + lrow;
            float bsv = bias[n];
            #pragma unroll
            for (int r = 0; r < 4; ++r) {
                int m = m0 + wm + i * 16 + lq * 4 + r;
                float v = acc[i][j][r] + bsv;
                v = v > 0.f ? v : 0.f;
                Hout[(size_t)m * H_ + n] = __float2bfloat16(v);
            }
        }
    }
}

// ===== GEMM2 (MFMA, split-K=8, atomic): phi[256][511] += h @ w2^T =====
// h [256][5120] bf16, w2 [511][5120] fp32. phi = d_out, pre-zeroed.
__global__ __launch_bounds__(256) void gemm2_mfma(
    const __hip_bfloat16* __restrict__ Hm, const float* __restrict__ W,
    float* __restrict__ phi)
{
    __shared__ char lds[16384];
    char* Ab = lds;
    char* Bb = lds + 8192;
    const int t = threadIdx.x;
    const int n0 = blockIdx.x * 64;
    const int m0 = blockIdx.y * 64;
    const int kbeg = blockIdx.z * 640;
    const int lane = t & 63, wave = t >> 6;
    const int wm = (wave & 1) * 32, wn = (wave >> 1) * 32;
    const int lrow = lane & 15, lq = lane >> 4;

    floatx4 acc[2][2] = {};

    const int ra_ = t >> 3;   // 0..31 rows (A), lanes 0..7 sweep chunks -> coalesced
    const int ca_ = t & 7;    // chunk 0..7
    const int rw_ = t >> 4;   // 0..15 rows (W), lanes 0..15 sweep float4s -> coalesced
    const int f4_ = t & 15;   // float4 index 0..15

    for (int k0 = 0; k0 < 640; k0 += 64) {
        __syncthreads();
        // A tile: 64 rows x 8 chunks of 8 bf16 (16B dwordx4 loads, aligned)
        #pragma unroll
        for (int q = 0; q < 2; ++q) {
            int row = ra_ + 32 * q;
            int4 raw = *(const int4*)(Hm + (size_t)(m0 + row) * H_ + kbeg + k0 + ca_ * 8);
            *(int4*)(Ab + sw_off(row, ca_)) = raw;
        }
        // W tile: 64 rows x 16 float4 (aligned), convert to bf16, 8B half-chunk writes
        #pragma unroll
        for (int q = 0; q < 4; ++q) {
            int row = rw_ + 16 * q;
            int n = n0 + row;
            float4 fv = make_float4(0.f, 0.f, 0.f, 0.f);
            if (n < D_) fv = *(const float4*)(W + (size_t)n * H_ + kbeg + k0 + f4_ * 4);
            unsigned int lo = (unsigned)f2bf(fv.x) | ((unsigned)f2bf(fv.y) << 16);
            unsigned int hi = (unsigned)f2bf(fv.z) | ((unsigned)f2bf(fv.w) << 16);
            int2 w8; w8.x = (int)lo; w8.y = (int)hi;
            int off = row * 128 + ((((f4_ >> 1) ^ (row & 7))) * 16) + (f4_ & 1) * 8;
            *(int2*)(Bb + off) = w8;
        }
        __syncthreads();
        #pragma unroll
        for (int ks = 0; ks < 2; ++ks) {
            int kc = ks * 4 + lq;
            I4S8 af[2], bf[2];
            #pragma unroll
            for (int i = 0; i < 2; ++i) {
                af[i].i4 = *(const int4*)(Ab + sw_off(wm + i * 16 + lrow, kc));
                bf[i].i4 = *(const int4*)(Bb + sw_off(wn + i * 16 + lrow, kc));
            }
            #pragma unroll
            for (int i = 0; i < 2; ++i)
                #pragma unroll
                for (int j = 0; j < 2; ++j)
                    acc[i][j] = __builtin_amdgcn_mfma_f32_16x16x32_bf16(
                        af[i].s8, bf[j].s8, acc[i][j], 0, 0, 0);
        }
    }

    #pragma unroll
    for (int i = 0; i < 2; ++i) {
        #pragma unroll
        for (int j = 0; j < 2; ++j) {
            int n = n0 + wn + j * 16 + lrow;
            if (n < D_) {
                #pragma unroll
                for (int r = 0; r < 4; ++r) {
                    int m = m0 + wm + i * 16 + lq * 4 + r;
                    atomicAdd(&phi[(size_t)m * D_ + n], acc[i][j][r]);
                }
            }
        }
    }
}

// ====== quad + final fused: per-b flat BW read of inv_Theta_11, then output ======
__global__ __launch_bounds__(512) void quad_final(
    const float* __restrict__ Mmat, const float* __restrict__ b2,
    const float* __restrict__ stw1, const float* __restrict__ stb1,
    const float* __restrict__ stw2, const float* __restrict__ stb2,
    float* __restrict__ phi_out)
{
    __shared__ float p[D_ + 1];
    __shared__ float red[8];
    __shared__ float qsh;
    const int b = blockIdx.x;
    const int t = threadIdx.x;

    if (t < D_) p[t] = phi_out[(size_t)b * D_ + t] + b2[t];
    __syncthreads();

    const size_t base = (size_t)b * NTOT;
    const float* Mb = Mmat + base;
    const int a0 = (int)((4 - (base & 3)) & 3);   // scalars before 16B alignment
    float acc = 0.f;

    if (t < a0) {
        int f = t;
        int r = f / D_; int c = f - r * D_;
        acc += Mb[f] * p[r] * p[c];
    }
    const int nvec = (NTOT - a0) >> 2;
    for (int v = t; v < nvec; v += 512) {
        int f = a0 + v * 4;
        float4 mv = *(const float4*)(Mb + f);
        int f0 = f,     r0 = f0 / D_, c0 = f0 - r0 * D_;
        int f1 = f + 1, r1 = f1 / D_, c1 = f1 - r1 * D_;
        int f2 = f + 2, r2 = f2 / D_, c2 = f2 - r2 * D_;
        int f3 = f + 3, r3 = f3 / D_, c3 = f3 - r3 * D_;
        acc += mv.x * (p[r0] * p[c0]);
        acc += mv.y * (p[r1] * p[c1]);
        acc += mv.z * (p[r2] * p[c2]);
        acc += mv.w * (p[r3] * p[c3]);
    }
    const int tbeg = a0 + nvec * 4;
    if (t < NTOT - tbeg) {
        int f = tbeg + t;
        int r = f / D_; int c = f - r * D_;
        acc += Mb[f] * p[r] * p[c];
    }

    #pragma unroll
    for (int off = 32; off > 0; off >>= 1) acc += __shfl_down(acc, off, 64);
    if ((t & 63) == 0) red[t >> 6] = acc;
    __syncthreads();
    if (t == 0) {
        float s = 0.f;
        #pragma unroll
        for (int w = 0; w < 8; ++w) s += red[w];
        qsh = s;
    }
    __syncthreads();

    const float q = qsh;
    if (t < D_) {
        float x = p[t] / sqrtf(q);   // zeta = 1
        float lam = stb2[0];
        #pragma unroll
        for (int k = 0; k < 5; ++k) {
            float g = x * stw1[k] + stb1[k];
            g = g > 0.f ? g : 0.f;
            lam += g * stw2[k];
        }
        lam = fabsf(lam) * 0.1f;
        float ax = fabsf(x) - lam;
        ax = ax > 0.f ? ax : 0.f;
        float s = (x > 0.f) ? 1.f : ((x < 0.f) ? -1.f : 0.f);
        phi_out[(size_t)b * D_ + t] = s * ax;
    }
}

extern "C" void kernel_launch(void* const* d_in, const int* in_sizes, int n_in,
                              void* d_out, int out_size, void* d_ws, size_t ws_size,
                              hipStream_t stream)
{
    const float* theta = (const float*)d_in[0];   // [B, D]
    const float* invT  = (const float*)d_in[3];   // [B, D, D]
    const float* w1    = (const float*)d_in[6];   // [H, D]
    const float* b1    = (const float*)d_in[7];   // [H]
    const float* w2    = (const float*)d_in[8];   // [D, H]
    const float* b2    = (const float*)d_in[9];   // [D]
    const float* stw1  = (const float*)d_in[10];  // [5]
    const float* stb1  = (const float*)d_in[11];  // [5]
    const float* stw2  = (const float*)d_in[12];  // [5]
    const float* stb2  = (const float*)d_in[13];  // [1]
    float* out = (float*)d_out;

    // ws: only h (bf16) — 2,621,440 B, proven-safe footprint
    __hip_bfloat16* h = (__hip_bfloat16*)d_ws;

    // phi accumulates via atomics in d_out
    hipMemsetAsync(out, 0, (size_t)B_ * D_ * sizeof(float), stream);

    // h = relu(theta @ w1^T + b1): M=256, N=5120(80 tiles), K=511->512
    gemm1_mfma<<<dim3(80, 4), 256, 0, stream>>>(theta, w1, b1, h);

    // phi += h @ w2^T: M=256, N=511(8 tiles), K=5120, split-K=8
    gemm2_mfma<<<dim3(8, 4, 8), 256, 0, stream>>>(h, w2, out);

    // quad + normalize + st-MLP + soft-threshold (in place on d_out)
    quad_final<<<B_, 512, 0, stream>>>(invT, b2, stw1, stb1, stw2, stb2, out);
}